// Round 2
// 1075.165 us; speedup vs baseline: 1.0649x; 1.0649x over previous
//
#include <hip/hip_runtime.h>
#include <cstdint>
#include <cstddef>

#define T_TOK 10
#define NH 12
#define DH 32
#define DIM 384
#define QKVDIM 1152
#define NB 4            // batches per workgroup
#define MROWS 40        // valid rows per WG
#define XS_LD 392       // bf16 elems per row of x/O staging (384 + 8 pad)
#define QK_LD 776       // bf16 elems per row of q/k staging (768 + 8 pad)
#define SCALE 0.17677669529663689f   // 32^-0.5

// LDS layout (bytes):
//   [0, 37632)          xs   [48][392] bf16   (phase2 aliases as O, attn output)
//   [37632, 99712)      qk   [40][776] bf16   (Q cols 0..383 prescaled, K cols 384..767)
//                       (phase3 aliases as outstage [40][384] f32 = 61440 B)
//   [99712, 148864)     vt   [4][12][32][16] bf16  (V transposed: [bl][h][d][j])
//   [148864, 149776)    bias_lds [19*12] f32
#define QK_OFF   37632
#define VT_OFF   99712
#define BIAS_OFF 148864
#define LDS_BYTES 149776

typedef short bf16x8 __attribute__((ext_vector_type(8)));
typedef float f32x4  __attribute__((ext_vector_type(4)));

__device__ __forceinline__ unsigned short f2b(float f) {
    unsigned u = __float_as_uint(f);
    u = (u + 0x7FFFu + ((u >> 16) & 1u)) >> 16;   // RNE
    return (unsigned short)u;
}
__device__ __forceinline__ unsigned pack2(float a, float b) {
    return (unsigned)f2b(a) | ((unsigned)f2b(b) << 16);
}

// ---------------- K0: convert weights fp32 -> bf16 into workspace ----------------
__global__ void convert_weights(const float* __restrict__ qkv_w,
                                const float* __restrict__ proj_w,
                                unsigned short* __restrict__ wq,
                                unsigned short* __restrict__ wp) {
    int i = blockIdx.x * blockDim.x + threadIdx.x;   // unit = 4 floats
    const int N1 = QKVDIM * DIM / 4;                 // 110592
    const int N2 = DIM * DIM / 4;                    // 36864
    if (i < N1) {
        float4 v = ((const float4*)qkv_w)[i];
        uint2 o; o.x = pack2(v.x, v.y); o.y = pack2(v.z, v.w);
        ((uint2*)wq)[i] = o;
    } else if (i < N1 + N2) {
        int j = i - N1;
        float4 v = ((const float4*)proj_w)[j];
        uint2 o; o.x = pack2(v.x, v.y); o.y = pack2(v.z, v.w);
        ((uint2*)wp)[j] = o;
    }
}

// ---------------- K1: fused qkv-gemm + attention + proj ----------------
extern __shared__ char smem[];

__global__ __launch_bounds__(512, 2) void fused_attn(
    const float* __restrict__ x,
    const float* __restrict__ qkv_b,
    const float* __restrict__ proj_b,
    const float* __restrict__ bias_table,
    const unsigned short* __restrict__ wq,
    const unsigned short* __restrict__ wp,
    float* __restrict__ out)
{
    const int t    = threadIdx.x;
    const int wg   = blockIdx.x;
    const int wave = t >> 6;
    const int lane = t & 63;
    const int quad = lane >> 4;
    const int l16  = lane & 15;

    unsigned short* xs       = (unsigned short*)smem;               // [48][392]
    unsigned short* qk       = (unsigned short*)(smem + QK_OFF);    // [40][776]
    unsigned short* vt       = (unsigned short*)(smem + VT_OFF);    // [4][12][32][16]
    float*          outstage = (float*)(smem + QK_OFF);             // [40][384] (alias)
    float*          bias_lds = (float*)(smem + BIAS_OFF);           // [228]

    // ---------- phase 0: stage x -> LDS bf16, zero pads, load bias table ----------
    {
        const float4* x4 = (const float4*)(x + (size_t)wg * MROWS * DIM);
        for (int idx = t; idx < MROWS * 96; idx += 512) {   // 3840 float4 units
            int row = idx / 96, c4 = idx % 96;
            float4 v = x4[idx];
            uint2 o; o.x = pack2(v.x, v.y); o.y = pack2(v.z, v.w);
            *(uint2*)(xs + row * XS_LD + c4 * 4) = o;
        }
        // zero rows 40..47 cols 0..383 (MFMA A-tile padding)
        for (int idx = t; idx < 8 * 96; idx += 512) {
            int row = MROWS + idx / 96, c4 = idx % 96;
            *(uint2*)(xs + row * XS_LD + c4 * 4) = make_uint2(0u, 0u);
        }
        // zero vt entirely: j=10..15 pad slots must be 0.0 (never NaN) for PV MFMA
        for (int idx = t; idx < 3072; idx += 512)
            ((uint4*)vt)[idx] = make_uint4(0u, 0u, 0u, 0u);
        if (t < (2 * T_TOK - 1) * NH) bias_lds[t] = bias_table[t];
    }
    __syncthreads();

    // ---------- phase 1: QKV GEMM (q pre-scaled, bias added); V stored transposed ----------
    {
        #pragma unroll 1
        for (int g = 0; g < 3; ++g) {
            f32x4 acc[3][3] = {};
            #pragma unroll
            for (int kc = 0; kc < 12; ++kc) {
                int koff = kc * 32 + quad * 8;
                bf16x8 a0 = *(const bf16x8*)(xs + ( 0 + l16) * XS_LD + koff);
                bf16x8 a1 = *(const bf16x8*)(xs + (16 + l16) * XS_LD + koff);
                bf16x8 a2 = *(const bf16x8*)(xs + (32 + l16) * XS_LD + koff);
                bf16x8 b0 = *(const bf16x8*)(wq + (size_t)((wave + 8*(3*g+0))*16 + l16) * DIM + koff);
                bf16x8 b1 = *(const bf16x8*)(wq + (size_t)((wave + 8*(3*g+1))*16 + l16) * DIM + koff);
                bf16x8 b2 = *(const bf16x8*)(wq + (size_t)((wave + 8*(3*g+2))*16 + l16) * DIM + koff);
                acc[0][0] = __builtin_amdgcn_mfma_f32_16x16x32_bf16(a0, b0, acc[0][0], 0, 0, 0);
                acc[0][1] = __builtin_amdgcn_mfma_f32_16x16x32_bf16(a0, b1, acc[0][1], 0, 0, 0);
                acc[0][2] = __builtin_amdgcn_mfma_f32_16x16x32_bf16(a0, b2, acc[0][2], 0, 0, 0);
                acc[1][0] = __builtin_amdgcn_mfma_f32_16x16x32_bf16(a1, b0, acc[1][0], 0, 0, 0);
                acc[1][1] = __builtin_amdgcn_mfma_f32_16x16x32_bf16(a1, b1, acc[1][1], 0, 0, 0);
                acc[1][2] = __builtin_amdgcn_mfma_f32_16x16x32_bf16(a1, b2, acc[1][2], 0, 0, 0);
                acc[2][0] = __builtin_amdgcn_mfma_f32_16x16x32_bf16(a2, b0, acc[2][0], 0, 0, 0);
                acc[2][1] = __builtin_amdgcn_mfma_f32_16x16x32_bf16(a2, b1, acc[2][1], 0, 0, 0);
                acc[2][2] = __builtin_amdgcn_mfma_f32_16x16x32_bf16(a2, b2, acc[2][2], 0, 0, 0);
            }
            #pragma unroll
            for (int j = 0; j < 3; ++j) {
                int n = (wave + 8*(3*g+j)) * 16 + l16;   // global qkv column
                float qb = qkv_b[n];
                if (g < 2) {                              // Q (g==0) or K (g==1): row-major
                    float sc = (g == 0) ? SCALE : 1.0f;
                    #pragma unroll
                    for (int mt = 0; mt < 3; ++mt) {
                        #pragma unroll
                        for (int r = 0; r < 4; ++r) {
                            int m = mt * 16 + quad * 4 + r;
                            if (m < MROWS)
                                qk[m * QK_LD + n] = f2b((acc[mt][j][r] + qb) * sc);
                        }
                    }
                } else {                                  // V: transposed store vt[bl][h][d][j]
                    int h = (n - 2*DIM) >> 5;
                    int d = (n - 2*DIM) & 31;
                    #pragma unroll
                    for (int mt = 0; mt < 3; ++mt) {
                        #pragma unroll
                        for (int r = 0; r < 4; ++r) {
                            int m = mt * 16 + quad * 4 + r;
                            if (m < MROWS) {
                                int bl = (m * 205) >> 11;     // m/10 for m<40
                                int jt = m - bl * 10;
                                vt[((bl*NH + h)*DH + d)*16 + jt] = f2b(acc[mt][j][r] + qb);
                            }
                        }
                    }
                }
            }
        }
    }
    __syncthreads();

    // ---------- phase 2: MFMA attention; O (bf16) written into xs ----------
    {
        const int l16c = (l16 < T_TOK) ? l16 : (T_TOK - 1);   // clamp token index
        const int joff = (quad < 2) ? quad * 8 : 8;           // V k-read clamp (P=0 there)
        #pragma unroll 2
        for (int pp = 0; pp < 6; ++pp) {
            int p  = wave * 6 + pp;      // 48 (batch,head) pairs, 6 per wave
            int bl = p / NH, h = p % NH;
            int rowq = bl * T_TOK + l16c;
            // S^T = K * Q^T : A-frag = K row (l16=j), B-frag = Q row (l16=i)
            bf16x8 kf = *(const bf16x8*)(qk + rowq * QK_LD + DIM + h * DH + quad * 8);
            bf16x8 qf = *(const bf16x8*)(qk + rowq * QK_LD +       h * DH + quad * 8);
            f32x4 sv = {};
            sv = __builtin_amdgcn_mfma_f32_16x16x32_bf16(kf, qf, sv, 0, 0, 0);
            // lane holds S[i=l16][j=quad*4+r]; add rel-pos bias, mask j>=10
            float s[4];
            #pragma unroll
            for (int r = 0; r < 4; ++r) {
                int jj  = quad * 4 + r;
                int jjc = (jj < T_TOK) ? jj : (T_TOK - 1);
                float b = bias_lds[(l16c - jjc + T_TOK - 1) * NH + h];
                s[r] = (jj < T_TOK) ? (sv[r] + b) : -1.0e30f;
            }
            // softmax over j: local max/sum + quad-reduction (lanes l16, +16, +32, +48)
            float mx = fmaxf(fmaxf(s[0], s[1]), fmaxf(s[2], s[3]));
            mx = fmaxf(mx, __shfl_xor(mx, 16));
            mx = fmaxf(mx, __shfl_xor(mx, 32));
            float p0 = __expf(s[0] - mx), p1 = __expf(s[1] - mx);
            float p2 = __expf(s[2] - mx), p3 = __expf(s[3] - mx);
            float sl = p0 + p1 + p2 + p3;
            sl += __shfl_xor(sl, 16);
            sl += __shfl_xor(sl, 32);
            float rinv = 1.0f / sl;      // applied in f32 AFTER PV (precision)
            // redistribute P^T[j][i] -> PV A-frag P[i=l16][j=quad*8+e]
            unsigned w0 = pack2(p0, p1), w1 = pack2(p2, p3);
            int s0l = ((quad & 1) << 5) + l16;        // source lane of quad 2*qA
            unsigned d0 = (unsigned)__shfl((int)w0, s0l);
            unsigned d1 = (unsigned)__shfl((int)w1, s0l);
            unsigned d2 = (unsigned)__shfl((int)w0, s0l + 16);
            unsigned d3 = (unsigned)__shfl((int)w1, s0l + 16);
            if (quad >= 2) { d0 = 0; d1 = 0; d2 = 0; d3 = 0; }   // j>=16 -> P=0
            union { bf16x8 v; unsigned u[4]; } pa;
            pa.u[0] = d0; pa.u[1] = d1; pa.u[2] = d2; pa.u[3] = d3;
            // PV: B-frag = vt row (contiguous j) at d = l16 / 16+l16
            const unsigned short* vb = vt + (size_t)((bl*NH + h)*DH) * 16;
            bf16x8 v0 = *(const bf16x8*)(vb + ( 0 + l16) * 16 + joff);
            bf16x8 v1 = *(const bf16x8*)(vb + (16 + l16) * 16 + joff);
            f32x4 o0 = {}, o1 = {};
            o0 = __builtin_amdgcn_mfma_f32_16x16x32_bf16(pa.v, v0, o0, 0, 0, 0);
            o1 = __builtin_amdgcn_mfma_f32_16x16x32_bf16(pa.v, v1, o1, 0, 0, 0);
            // gather 1/sum for this lane's 4 output rows, scale, store O rows i<10
            #pragma unroll
            for (int r = 0; r < 4; ++r) {
                float rv = __shfl(rinv, quad * 4 + r);
                int i = quad * 4 + r;
                if (i < T_TOK) {
                    int m = bl * T_TOK + i;
                    xs[m * XS_LD + h * DH +      l16] = f2b(o0[r] * rv);
                    xs[m * XS_LD + h * DH + 16 + l16] = f2b(o1[r] * rv);
                }
            }
        }
    }
    __syncthreads();

    // ---------- phase 3: proj GEMM (A = O in xs), stage fp32 in qk region ----------
    {
        f32x4 acc[3][3] = {};
        #pragma unroll
        for (int kc = 0; kc < 12; ++kc) {
            int koff = kc * 32 + quad * 8;
            bf16x8 a0 = *(const bf16x8*)(xs + ( 0 + l16) * XS_LD + koff);
            bf16x8 a1 = *(const bf16x8*)(xs + (16 + l16) * XS_LD + koff);
            bf16x8 a2 = *(const bf16x8*)(xs + (32 + l16) * XS_LD + koff);
            bf16x8 b0 = *(const bf16x8*)(wp + (size_t)((wave +  0)*16 + l16) * DIM + koff);
            bf16x8 b1 = *(const bf16x8*)(wp + (size_t)((wave +  8)*16 + l16) * DIM + koff);
            bf16x8 b2 = *(const bf16x8*)(wp + (size_t)((wave + 16)*16 + l16) * DIM + koff);
            acc[0][0] = __builtin_amdgcn_mfma_f32_16x16x32_bf16(a0, b0, acc[0][0], 0, 0, 0);
            acc[0][1] = __builtin_amdgcn_mfma_f32_16x16x32_bf16(a0, b1, acc[0][1], 0, 0, 0);
            acc[0][2] = __builtin_amdgcn_mfma_f32_16x16x32_bf16(a0, b2, acc[0][2], 0, 0, 0);
            acc[1][0] = __builtin_amdgcn_mfma_f32_16x16x32_bf16(a1, b0, acc[1][0], 0, 0, 0);
            acc[1][1] = __builtin_amdgcn_mfma_f32_16x16x32_bf16(a1, b1, acc[1][1], 0, 0, 0);
            acc[1][2] = __builtin_amdgcn_mfma_f32_16x16x32_bf16(a1, b2, acc[1][2], 0, 0, 0);
            acc[2][0] = __builtin_amdgcn_mfma_f32_16x16x32_bf16(a2, b0, acc[2][0], 0, 0, 0);
            acc[2][1] = __builtin_amdgcn_mfma_f32_16x16x32_bf16(a2, b1, acc[2][1], 0, 0, 0);
            acc[2][2] = __builtin_amdgcn_mfma_f32_16x16x32_bf16(a2, b2, acc[2][2], 0, 0, 0);
        }
        #pragma unroll
        for (int j = 0; j < 3; ++j) {
            int c = (wave + 8*j) * 16 + l16;
            #pragma unroll
            for (int mt = 0; mt < 3; ++mt) {
                #pragma unroll
                for (int r = 0; r < 4; ++r) {
                    int m = mt * 16 + quad * 4 + r;
                    if (m < MROWS)
                        outstage[m * DIM + c] = acc[mt][j][r];
                }
            }
        }
    }
    __syncthreads();

    // ---------- phase 4: coalesced store (+ proj bias) ----------
    {
        const float4* st4 = (const float4*)outstage;
        const float4* pb4 = (const float4*)proj_b;
        float4* out4 = (float4*)(out + (size_t)wg * MROWS * DIM);
        for (int idx = t; idx < MROWS * 96; idx += 512) {
            int c4 = idx % 96;
            float4 v = st4[idx];
            float4 b = pb4[c4];
            float4 r; r.x = v.x + b.x; r.y = v.y + b.y; r.z = v.z + b.z; r.w = v.w + b.w;
            out4[idx] = r;
        }
    }
}

extern "C" void kernel_launch(void* const* d_in, const int* in_sizes, int n_in,
                              void* d_out, int out_size, void* d_ws, size_t ws_size,
                              hipStream_t stream) {
    const float* x          = (const float*)d_in[0];
    const float* qkv_b      = (const float*)d_in[1];
    const float* qkv_b_     = (const float*)d_in[2];
    const float* proj_w     = (const float*)d_in[3];
    const float* proj_b     = (const float*)d_in[4];
    const float* bias_table = (const float*)d_in[5];
    // note: d_in[1]=qkv_w, d_in[2]=qkv_b (names above kept positional)
    const float* qkv_w = qkv_b;
    const float* qkv_bias = qkv_b_;

    unsigned short* wq = (unsigned short*)d_ws;              // [1152][384] bf16
    unsigned short* wp = wq + (size_t)QKVDIM * DIM;          // [384][384] bf16
    float* out = (float*)d_out;

    convert_weights<<<576, 256, 0, stream>>>(qkv_w, proj_w, wq, wp);

    hipFuncSetAttribute((const void*)fused_attn,
                        hipFuncAttributeMaxDynamicSharedMemorySize, LDS_BYTES);
    fused_attn<<<16384 / NB, 512, LDS_BYTES, stream>>>(x, qkv_bias, proj_b, bias_table, wq, wp, out);
}

// Round 3
// 1074.064 us; speedup vs baseline: 1.0660x; 1.0010x over previous
//
#include <hip/hip_runtime.h>
#include <cstdint>
#include <cstddef>

#define T_TOK 10
#define NH 12
#define DH 32
#define DIM 384
#define QKVDIM 1152
#define NB 4            // batches per group
#define MROWS 40        // valid rows per group
#define XS_LD 392       // bf16 elems per row of x/O staging (384 + 8 pad)
#define QK_LD 776       // bf16 elems per row of q/k staging (768 + 8 pad)
#define SCALE 0.17677669529663689f   // 32^-0.5
#define NBLK 256        // persistent blocks (1 per CU; LDS-bound)
#define NIT  16         // groups per block: 16384/NB/NBLK

// LDS layout (bytes):
//   [0, 37632)          xs   [48][392] bf16   (phase2 re-uses as O, attn output)
//   [37632, 99712)      qk   [40][776] bf16   (Q cols 0..383 prescaled, K cols 384..767)
//   [99712, 148864)     vt   [4][12][32][16] bf16  (V^T: [bl][h][d][j], j XOR-swizzled)
//   [148864, 149776)    bias_lds [19*12] f32
#define QK_OFF   37632
#define VT_OFF   99712
#define BIAS_OFF 148864
#define LDS_BYTES 149776

typedef short bf16x8 __attribute__((ext_vector_type(8)));
typedef float f32x4  __attribute__((ext_vector_type(4)));

__device__ __forceinline__ unsigned short f2b(float f) {
    unsigned u = __float_as_uint(f);
    u = (u + 0x7FFFu + ((u >> 16) & 1u)) >> 16;   // RNE
    return (unsigned short)u;
}
__device__ __forceinline__ unsigned pack2(float a, float b) {
    return (unsigned)f2b(a) | ((unsigned)f2b(b) << 16);
}

// ---------------- K0: convert weights fp32 -> bf16 into workspace ----------------
__global__ void convert_weights(const float* __restrict__ qkv_w,
                                const float* __restrict__ proj_w,
                                unsigned short* __restrict__ wq,
                                unsigned short* __restrict__ wp) {
    int i = blockIdx.x * blockDim.x + threadIdx.x;   // unit = 4 floats
    const int N1 = QKVDIM * DIM / 4;                 // 110592
    const int N2 = DIM * DIM / 4;                    // 36864
    if (i < N1) {
        float4 v = ((const float4*)qkv_w)[i];
        uint2 o; o.x = pack2(v.x, v.y); o.y = pack2(v.z, v.w);
        ((uint2*)wq)[i] = o;
    } else if (i < N1 + N2) {
        int j = i - N1;
        float4 v = ((const float4*)proj_w)[j];
        uint2 o; o.x = pack2(v.x, v.y); o.y = pack2(v.z, v.w);
        ((uint2*)wp)[j] = o;
    }
}

// ---------------- K1: persistent fused qkv-gemm + attention + proj ----------------
extern __shared__ char smem[];

__global__ __launch_bounds__(512, 2) void fused_attn(
    const float* __restrict__ x,
    const float* __restrict__ qkv_b,
    const float* __restrict__ proj_b,
    const float* __restrict__ bias_table,
    const unsigned short* __restrict__ wq,
    const unsigned short* __restrict__ wp,
    float* __restrict__ out)
{
    const int t    = threadIdx.x;
    const int b    = blockIdx.x;
    const int wave = t >> 6;
    const int lane = t & 63;
    const int quad = lane >> 4;
    const int l16  = lane & 15;

    unsigned short* xs       = (unsigned short*)smem;               // [48][392]
    unsigned short* qk       = (unsigned short*)(smem + QK_OFF);    // [40][776]
    unsigned short* vt       = (unsigned short*)(smem + VT_OFF);    // [4][12][32][16]
    float*          bias_lds = (float*)(smem + BIAS_OFF);           // [228]

    // ---------- persistent prologue: biases to regs, one-time zero fills ----------
    float pb[3];
    float qbr[3][3];
    #pragma unroll
    for (int j = 0; j < 3; ++j) pb[j] = proj_b[(wave + 8*j) * 16 + l16];
    #pragma unroll
    for (int g = 0; g < 3; ++g)
        #pragma unroll
        for (int j = 0; j < 3; ++j)
            qbr[g][j] = qkv_b[(wave + 8*(3*g+j)) * 16 + l16];

    // zero xs pad rows 40..47 cols 0..383 (MFMA A-tile padding; never overwritten)
    for (int idx = t; idx < 8 * 96; idx += 512) {
        int row = MROWS + idx / 96, c4 = idx % 96;
        *(uint2*)(xs + row * XS_LD + c4 * 4) = make_uint2(0u, 0u);
    }
    // zero vt entirely: pad j slots must be 0.0 (never NaN) for PV MFMA
    for (int idx = t; idx < 3072; idx += 512)
        ((uint4*)vt)[idx] = make_uint4(0u, 0u, 0u, 0u);
    if (t < (2 * T_TOK - 1) * NH) bias_lds[t] = bias_table[t];

    // ---------- prefetch x for group it=0 ----------
    float4 px[8];
    {
        const float4* xg = (const float4*)(x + (size_t)b * MROWS * DIM);
        #pragma unroll
        for (int i = 0; i < 8; ++i) {
            int idx = i * 512 + t;
            if (idx < MROWS * 96) px[i] = xg[idx];
        }
    }

    for (int it = 0; it < NIT; ++it) {
        const size_t g = (size_t)it * NBLK + b;

        // ---------- phase 0: write prefetched x into LDS (bf16) ----------
        #pragma unroll
        for (int i = 0; i < 8; ++i) {
            int idx = i * 512 + t;
            if (idx < MROWS * 96) {
                int row = idx / 96, c4 = idx % 96;
                uint2 o; o.x = pack2(px[i].x, px[i].y); o.y = pack2(px[i].z, px[i].w);
                *(uint2*)(xs + row * XS_LD + c4 * 4) = o;
            }
        }
        __syncthreads();

        // ---------- phase 1: QKV GEMM (q pre-scaled, bias added); V stored transposed ----------
        {
            #pragma unroll 1
            for (int gg = 0; gg < 3; ++gg) {
                f32x4 acc[3][3] = {};
                #pragma unroll
                for (int kc = 0; kc < 12; ++kc) {
                    int koff = kc * 32 + quad * 8;
                    bf16x8 a0 = *(const bf16x8*)(xs + ( 0 + l16) * XS_LD + koff);
                    bf16x8 a1 = *(const bf16x8*)(xs + (16 + l16) * XS_LD + koff);
                    bf16x8 a2 = *(const bf16x8*)(xs + (32 + l16) * XS_LD + koff);
                    bf16x8 b0 = *(const bf16x8*)(wq + (size_t)((wave + 8*(3*gg+0))*16 + l16) * DIM + koff);
                    bf16x8 b1 = *(const bf16x8*)(wq + (size_t)((wave + 8*(3*gg+1))*16 + l16) * DIM + koff);
                    bf16x8 b2 = *(const bf16x8*)(wq + (size_t)((wave + 8*(3*gg+2))*16 + l16) * DIM + koff);
                    acc[0][0] = __builtin_amdgcn_mfma_f32_16x16x32_bf16(a0, b0, acc[0][0], 0, 0, 0);
                    acc[0][1] = __builtin_amdgcn_mfma_f32_16x16x32_bf16(a0, b1, acc[0][1], 0, 0, 0);
                    acc[0][2] = __builtin_amdgcn_mfma_f32_16x16x32_bf16(a0, b2, acc[0][2], 0, 0, 0);
                    acc[1][0] = __builtin_amdgcn_mfma_f32_16x16x32_bf16(a1, b0, acc[1][0], 0, 0, 0);
                    acc[1][1] = __builtin_amdgcn_mfma_f32_16x16x32_bf16(a1, b1, acc[1][1], 0, 0, 0);
                    acc[1][2] = __builtin_amdgcn_mfma_f32_16x16x32_bf16(a1, b2, acc[1][2], 0, 0, 0);
                    acc[2][0] = __builtin_amdgcn_mfma_f32_16x16x32_bf16(a2, b0, acc[2][0], 0, 0, 0);
                    acc[2][1] = __builtin_amdgcn_mfma_f32_16x16x32_bf16(a2, b1, acc[2][1], 0, 0, 0);
                    acc[2][2] = __builtin_amdgcn_mfma_f32_16x16x32_bf16(a2, b2, acc[2][2], 0, 0, 0);
                }
                #pragma unroll
                for (int j = 0; j < 3; ++j) {
                    int n = (wave + 8*(3*gg+j)) * 16 + l16;   // global qkv column
                    float qb = qbr[gg][j];
                    if (gg < 2) {                             // Q (gg==0) or K (gg==1): row-major
                        float sc = (gg == 0) ? SCALE : 1.0f;
                        #pragma unroll
                        for (int mt = 0; mt < 3; ++mt) {
                            #pragma unroll
                            for (int r = 0; r < 4; ++r) {
                                int m = mt * 16 + quad * 4 + r;
                                if (m < MROWS)
                                    qk[m * QK_LD + n] = f2b((acc[mt][j][r] + qb) * sc);
                            }
                        }
                    } else {                                  // V: transposed store vt[bl][h][d][j^s]
                        int h = (n - 2*DIM) >> 5;
                        int d = (n - 2*DIM) & 31;
                        int sd = ((d >> 2) & 1) << 3;         // bank swizzle (j-half XOR)
                        #pragma unroll
                        for (int mt = 0; mt < 3; ++mt) {
                            #pragma unroll
                            for (int r = 0; r < 4; ++r) {
                                int m = mt * 16 + quad * 4 + r;
                                if (m < MROWS) {
                                    int bl = (m * 205) >> 11;     // m/10 for m<40
                                    int jt = m - bl * 10;
                                    vt[((bl*NH + h)*DH + d)*16 + (jt ^ sd)] = f2b(acc[mt][j][r] + qb);
                                }
                            }
                        }
                    }
                }
            }
        }
        __syncthreads();

        // ---------- phase 2: MFMA attention; O (bf16) written into xs ----------
        {
            const int l16c = (l16 < T_TOK) ? l16 : (T_TOK - 1);   // clamp token index
            const int joff = (quad < 2) ? quad * 8 : 8;           // V k-read clamp (P=0 there)
            const int sw   = ((l16 >> 2) & 1) << 3;               // vt read swizzle (row d=l16 / 16+l16)
            const int joff2 = joff ^ sw;
            #pragma unroll 2
            for (int pp = 0; pp < 6; ++pp) {
                int p  = wave * 6 + pp;      // 48 (batch,head) pairs, 6 per wave
                int bl = p / NH, h = p % NH;
                int rowq = bl * T_TOK + l16c;
                // S^T = K * Q^T : A-frag = K row (l16=j), B-frag = Q row (l16=i)
                bf16x8 kf = *(const bf16x8*)(qk + rowq * QK_LD + DIM + h * DH + quad * 8);
                bf16x8 qf = *(const bf16x8*)(qk + rowq * QK_LD +       h * DH + quad * 8);
                f32x4 sv = {};
                sv = __builtin_amdgcn_mfma_f32_16x16x32_bf16(kf, qf, sv, 0, 0, 0);
                // lane holds S[i=l16][j=quad*4+r]; add rel-pos bias, mask j>=10
                float s[4];
                #pragma unroll
                for (int r = 0; r < 4; ++r) {
                    int jj  = quad * 4 + r;
                    int jjc = (jj < T_TOK) ? jj : (T_TOK - 1);
                    float bb = bias_lds[(l16c - jjc + T_TOK - 1) * NH + h];
                    s[r] = (jj < T_TOK) ? (sv[r] + bb) : -1.0e30f;
                }
                // softmax over j: local max/sum + quad-reduction
                float mx = fmaxf(fmaxf(s[0], s[1]), fmaxf(s[2], s[3]));
                mx = fmaxf(mx, __shfl_xor(mx, 16));
                mx = fmaxf(mx, __shfl_xor(mx, 32));
                float p0 = __expf(s[0] - mx), p1 = __expf(s[1] - mx);
                float p2 = __expf(s[2] - mx), p3 = __expf(s[3] - mx);
                float sl = p0 + p1 + p2 + p3;
                sl += __shfl_xor(sl, 16);
                sl += __shfl_xor(sl, 32);
                float rinv = 1.0f / sl;      // applied in f32 AFTER PV
                // redistribute P^T[j][i] -> PV A-frag P[i=l16][j=quad*8+e]
                unsigned w0 = pack2(p0, p1), w1 = pack2(p2, p3);
                int s0l = ((quad & 1) << 5) + l16;
                unsigned d0 = (unsigned)__shfl((int)w0, s0l);
                unsigned d1 = (unsigned)__shfl((int)w1, s0l);
                unsigned d2 = (unsigned)__shfl((int)w0, s0l + 16);
                unsigned d3 = (unsigned)__shfl((int)w1, s0l + 16);
                if (quad >= 2) { d0 = 0; d1 = 0; d2 = 0; d3 = 0; }   // j>=16 -> P=0
                union { bf16x8 v; unsigned u[4]; } pa;
                pa.u[0] = d0; pa.u[1] = d1; pa.u[2] = d2; pa.u[3] = d3;
                // PV: B-frag = vt row (contiguous swizzled j) at d = l16 / 16+l16
                const unsigned short* vb = vt + (size_t)((bl*NH + h)*DH) * 16;
                bf16x8 v0 = *(const bf16x8*)(vb + ( 0 + l16) * 16 + joff2);
                bf16x8 v1 = *(const bf16x8*)(vb + (16 + l16) * 16 + joff2);
                f32x4 o0 = {}, o1 = {};
                o0 = __builtin_amdgcn_mfma_f32_16x16x32_bf16(pa.v, v0, o0, 0, 0, 0);
                o1 = __builtin_amdgcn_mfma_f32_16x16x32_bf16(pa.v, v1, o1, 0, 0, 0);
                // gather 1/sum per output row, scale, store O rows i<10
                #pragma unroll
                for (int r = 0; r < 4; ++r) {
                    float rv = __shfl(rinv, quad * 4 + r);
                    int i = quad * 4 + r;
                    if (i < T_TOK) {
                        int m = bl * T_TOK + i;
                        xs[m * XS_LD + h * DH +      l16] = f2b(o0[r] * rv);
                        xs[m * XS_LD + h * DH + 16 + l16] = f2b(o1[r] * rv);
                    }
                }
            }
        }

        // ---------- T14: prefetch next group's x while phase 3 runs ----------
        if (it + 1 < NIT) {
            const float4* xg = (const float4*)(x + ((size_t)(it+1) * NBLK + b) * MROWS * DIM);
            #pragma unroll
            for (int i = 0; i < 8; ++i) {
                int idx = i * 512 + t;
                if (idx < MROWS * 96) px[i] = xg[idx];
            }
        }
        __syncthreads();

        // ---------- phase 3: proj GEMM (A = O in xs), direct reg->global store ----------
        {
            f32x4 acc[3][3] = {};
            #pragma unroll
            for (int kc = 0; kc < 12; ++kc) {
                int koff = kc * 32 + quad * 8;
                bf16x8 a0 = *(const bf16x8*)(xs + ( 0 + l16) * XS_LD + koff);
                bf16x8 a1 = *(const bf16x8*)(xs + (16 + l16) * XS_LD + koff);
                bf16x8 a2 = *(const bf16x8*)(xs + (32 + l16) * XS_LD + koff);
                bf16x8 b0 = *(const bf16x8*)(wp + (size_t)((wave +  0)*16 + l16) * DIM + koff);
                bf16x8 b1 = *(const bf16x8*)(wp + (size_t)((wave +  8)*16 + l16) * DIM + koff);
                bf16x8 b2 = *(const bf16x8*)(wp + (size_t)((wave + 16)*16 + l16) * DIM + koff);
                acc[0][0] = __builtin_amdgcn_mfma_f32_16x16x32_bf16(a0, b0, acc[0][0], 0, 0, 0);
                acc[0][1] = __builtin_amdgcn_mfma_f32_16x16x32_bf16(a0, b1, acc[0][1], 0, 0, 0);
                acc[0][2] = __builtin_amdgcn_mfma_f32_16x16x32_bf16(a0, b2, acc[0][2], 0, 0, 0);
                acc[1][0] = __builtin_amdgcn_mfma_f32_16x16x32_bf16(a1, b0, acc[1][0], 0, 0, 0);
                acc[1][1] = __builtin_amdgcn_mfma_f32_16x16x32_bf16(a1, b1, acc[1][1], 0, 0, 0);
                acc[1][2] = __builtin_amdgcn_mfma_f32_16x16x32_bf16(a1, b2, acc[1][2], 0, 0, 0);
                acc[2][0] = __builtin_amdgcn_mfma_f32_16x16x32_bf16(a2, b0, acc[2][0], 0, 0, 0);
                acc[2][1] = __builtin_amdgcn_mfma_f32_16x16x32_bf16(a2, b1, acc[2][1], 0, 0, 0);
                acc[2][2] = __builtin_amdgcn_mfma_f32_16x16x32_bf16(a2, b2, acc[2][2], 0, 0, 0);
            }
            float* og = out + g * (MROWS * DIM);
            #pragma unroll
            for (int j = 0; j < 3; ++j) {
                int c = (wave + 8*j) * 16 + l16;
                float pbv = pb[j];
                #pragma unroll
                for (int mt = 0; mt < 3; ++mt) {
                    #pragma unroll
                    for (int r = 0; r < 4; ++r) {
                        int m = mt * 16 + quad * 4 + r;
                        if (m < MROWS)
                            og[m * DIM + c] = acc[mt][j][r] + pbv;
                    }
                }
            }
        }
        __syncthreads();   // xs (O) reads done before next iteration's x ds_write
    }
}

extern "C" void kernel_launch(void* const* d_in, const int* in_sizes, int n_in,
                              void* d_out, int out_size, void* d_ws, size_t ws_size,
                              hipStream_t stream) {
    const float* x          = (const float*)d_in[0];
    const float* qkv_w      = (const float*)d_in[1];
    const float* qkv_b      = (const float*)d_in[2];
    const float* proj_w     = (const float*)d_in[3];
    const float* proj_b     = (const float*)d_in[4];
    const float* bias_table = (const float*)d_in[5];

    unsigned short* wq = (unsigned short*)d_ws;              // [1152][384] bf16
    unsigned short* wp = wq + (size_t)QKVDIM * DIM;          // [384][384] bf16
    float* out = (float*)d_out;

    convert_weights<<<576, 256, 0, stream>>>(qkv_w, proj_w, wq, wp);

    hipFuncSetAttribute((const void*)fused_attn,
                        hipFuncAttributeMaxDynamicSharedMemorySize, LDS_BYTES);
    fused_attn<<<NBLK, 512, LDS_BYTES, stream>>>(x, qkv_b, proj_b, bias_table, wq, wp, out);
}